// Round 1
// baseline (550.725 us; speedup 1.0000x reference)
//
#include <hip/hip_runtime.h>
#include <math.h>

#define NBATCH 8
#define HWDIM  56
#define CDIM   256
#define NWIN   7
#define P2     49
#define HEADS  8
#define TOPK   4
#define SCALE  0.0625f
#define NPIX   (NBATCH*HWDIM*HWDIM)   // 25088

// ---------------------------------------------------------------------------
// Generic fp32 GEMM: C[M][Nout] = A[M][256] @ B[256][Nout] + bias
// BM=BN=128, BK=16, 256 threads, 8x8 micro-tile.
// Output columns are split into up to three 256-wide buffers (QKV case).
// ---------------------------------------------------------------------------
__global__ __launch_bounds__(256) void gemm_f32(
    const float* __restrict__ A, const float* __restrict__ B,
    const float* __restrict__ bias,
    float* __restrict__ C0, float* __restrict__ C1, float* __restrict__ C2,
    int M, int Nout)
{
  __shared__ float As[16][128];
  __shared__ float Bs[16][128];
  const int bm = blockIdx.x, bn = blockIdx.y;
  const int tid = threadIdx.x;
  const int tx = tid & 15, ty = tid >> 4;
  const int row0 = bm * 128, col0 = bn * 128;

  const int ar = tid >> 2;            // 0..63
  const int ak = (tid & 3) << 2;      // 0,4,8,12
  const int bk = tid >> 4;            // 0..15
  const int bc = (tid & 15) << 3;     // 0..120

  float acc[8][8];
  #pragma unroll
  for (int i = 0; i < 8; ++i)
    #pragma unroll
    for (int j = 0; j < 8; ++j) acc[i][j] = 0.f;

  for (int k0 = 0; k0 < 256; k0 += 16) {
    float4 a0 = *(const float4*)&A[(size_t)(row0 + ar)      * 256 + k0 + ak];
    float4 a1 = *(const float4*)&A[(size_t)(row0 + ar + 64) * 256 + k0 + ak];
    float4 b0 = *(const float4*)&B[(size_t)(k0 + bk) * Nout + col0 + bc];
    float4 b1 = *(const float4*)&B[(size_t)(k0 + bk) * Nout + col0 + bc + 4];
    As[ak + 0][ar] = a0.x; As[ak + 1][ar] = a0.y;
    As[ak + 2][ar] = a0.z; As[ak + 3][ar] = a0.w;
    As[ak + 0][ar + 64] = a1.x; As[ak + 1][ar + 64] = a1.y;
    As[ak + 2][ar + 64] = a1.z; As[ak + 3][ar + 64] = a1.w;
    *(float4*)&Bs[bk][bc]     = b0;
    *(float4*)&Bs[bk][bc + 4] = b1;
    __syncthreads();
    #pragma unroll
    for (int kk = 0; kk < 16; ++kk) {
      float4 av0 = *(const float4*)&As[kk][ty * 8];
      float4 av1 = *(const float4*)&As[kk][ty * 8 + 4];
      float4 bv0 = *(const float4*)&Bs[kk][tx * 8];
      float4 bv1 = *(const float4*)&Bs[kk][tx * 8 + 4];
      float av[8] = {av0.x, av0.y, av0.z, av0.w, av1.x, av1.y, av1.z, av1.w};
      float bv[8] = {bv0.x, bv0.y, bv0.z, bv0.w, bv1.x, bv1.y, bv1.z, bv1.w};
      #pragma unroll
      for (int i = 0; i < 8; ++i)
        #pragma unroll
        for (int j = 0; j < 8; ++j)
          acc[i][j] = fmaf(av[i], bv[j], acc[i][j]);
    }
    __syncthreads();
  }

  float* Cp = (bn < 2) ? C0 : (bn < 4) ? C1 : C2;
  const int lc = ((bn & 1) << 7) + (tx << 3);
  float bj[8];
  #pragma unroll
  for (int j = 0; j < 8; ++j) bj[j] = bias[col0 + (tx << 3) + j];
  #pragma unroll
  for (int i = 0; i < 8; ++i) {
    size_t row = (size_t)(row0 + ty * 8 + i);
    float4 w0, w1;
    w0.x = acc[i][0] + bj[0]; w0.y = acc[i][1] + bj[1];
    w0.z = acc[i][2] + bj[2]; w0.w = acc[i][3] + bj[3];
    w1.x = acc[i][4] + bj[4]; w1.y = acc[i][5] + bj[5];
    w1.z = acc[i][6] + bj[6]; w1.w = acc[i][7] + bj[7];
    *(float4*)&Cp[row * 256 + lc]     = w0;
    *(float4*)&Cp[row * 256 + lc + 4] = w1;
  }
}

// ---------------------------------------------------------------------------
// Per-window means of q and k  (grid = N*P2, 256 threads = channels)
// ---------------------------------------------------------------------------
__global__ __launch_bounds__(256) void win_means(
    const float* __restrict__ q_img, const float* __restrict__ k_img,
    float* __restrict__ q_win, float* __restrict__ k_win)
{
  const int b = blockIdx.x;
  const int n = b / P2, p = b - n * P2;
  const int wj = p / NWIN, wi = p - wj * NWIN;
  const int c = threadIdx.x;
  float sq = 0.f, sk = 0.f;
  for (int t = 0; t < 64; ++t) {
    const int y = wj * 8 + (t >> 3);
    const int x = wi * 8 + (t & 7);
    const size_t off = ((size_t)((n * HWDIM + y) * HWDIM + x)) * 256 + c;
    sq += q_img[off];
    sk += k_img[off];
  }
  q_win[(size_t)b * 256 + c] = sq * (1.f / 64.f);
  k_win[(size_t)b * 256 + c] = sk * (1.f / 64.f);
}

// ---------------------------------------------------------------------------
// Routing: 49x49 logits per image, top-4 per row  (grid = N, 256 threads)
// ---------------------------------------------------------------------------
__global__ __launch_bounds__(256) void routing_topk(
    const float* __restrict__ q_win, const float* __restrict__ k_win,
    int* __restrict__ r_idx)
{
  __shared__ float logit[P2][P2 + 1];
  const int n = blockIdx.x, tid = threadIdx.x;
  const float* qb = q_win + (size_t)n * P2 * 256;
  const float* kb = k_win + (size_t)n * P2 * 256;
  for (int idx = tid; idx < P2 * P2; idx += 256) {
    const int p = idx / P2, qq = idx - p * P2;
    float acc = 0.f;
    for (int c = 0; c < 256; ++c)
      acc = fmaf(qb[p * 256 + c], kb[qq * 256 + c], acc);
    logit[p][qq] = acc * SCALE;
  }
  __syncthreads();
  if (tid < P2) {
    float bv0 = -3e38f, bv1 = -3e38f, bv2 = -3e38f, bv3 = -3e38f;
    int bi0 = 0, bi1 = 0, bi2 = 0, bi3 = 0;
    for (int qq = 0; qq < P2; ++qq) {
      const float v = logit[tid][qq];
      if (v > bv0) { bv3=bv2; bi3=bi2; bv2=bv1; bi2=bi1; bv1=bv0; bi1=bi0; bv0=v; bi0=qq; }
      else if (v > bv1) { bv3=bv2; bi3=bi2; bv2=bv1; bi2=bi1; bv1=v; bi1=qq; }
      else if (v > bv2) { bv3=bv2; bi3=bi2; bv2=v; bi2=qq; }
      else if (v > bv3) { bv3=v; bi3=qq; }
    }
    int* rp = r_idx + (size_t)(n * P2 + tid) * TOPK;
    rp[0] = bi0; rp[1] = bi1; rp[2] = bi2; rp[3] = bi3;
  }
}

// ---------------------------------------------------------------------------
// Gathered attention. grid = N*P2*HEADS, 256 threads.
// Thread = (rp 0..31: query-row pair, qt 0..7: key octant of 32 keys).
// K/V staged in 64 KB LDS with XOR float4 swizzle (ip = i ^ (row&7)).
// ---------------------------------------------------------------------------
__global__ __launch_bounds__(256) void attn_kernel(
    const float* __restrict__ q_img, const float* __restrict__ k_img,
    const float* __restrict__ v_img, const int* __restrict__ r_idx,
    float* __restrict__ out_img)
{
  __shared__ float kls[256][32];
  __shared__ float vls[256][32];
  const int b = blockIdx.x;
  const int head = b & 7;
  const int np = b >> 3;
  const int n = np / P2, p = np - n * P2;
  const int tid = threadIdx.x;

  const int s0i = r_idx[np * 4 + 0];
  const int s1i = r_idx[np * 4 + 1];
  const int s2i = r_idx[np * 4 + 2];
  const int s3i = r_idx[np * 4 + 3];

  // stage K/V: 4 windows x 64 pixels x 32 channels each
  for (int it = 0; it < 32; ++it) {
    const int idx = tid + it * 256;
    const int c   = idx & 31;
    const int pix = (idx >> 5) & 63;
    const int s   = idx >> 11;
    const int wsel = (s == 0) ? s0i : (s == 1) ? s1i : (s == 2) ? s2i : s3i;
    const int y = (wsel / NWIN) * 8 + (pix >> 3);
    const int x = (wsel % NWIN) * 8 + (pix & 7);
    const size_t off = ((size_t)((n * HWDIM + y) * HWDIM + x)) * 256 + head * 32 + c;
    const int row = s * 64 + pix;
    const int cph = ((((c >> 2) ^ (row & 7)) << 2) | (c & 3));
    kls[row][cph] = k_img[off];
    vls[row][cph] = v_img[off];
  }
  __syncthreads();

  const int rp = tid >> 3;            // 0..31
  const int qt = tid & 7;             // 0..7
  const int wjp = p / NWIN, wip = p - wjp * NWIN;
  const int t0 = rp * 2, t1 = t0 + 1;
  const int y0 = wjp * 8 + (t0 >> 3), x0 = wip * 8 + (t0 & 7);
  const int y1 = wjp * 8 + (t1 >> 3), x1 = wip * 8 + (t1 & 7);
  const float* qp0 = &q_img[((size_t)((n * HWDIM + y0) * HWDIM + x0)) * 256 + head * 32];
  const float* qp1 = &q_img[((size_t)((n * HWDIM + y1) * HWDIM + x1)) * 256 + head * 32];

  float4 q0[8], q1[8];
  #pragma unroll
  for (int i = 0; i < 8; ++i) {
    q0[i] = *(const float4*)&qp0[4 * i];
    q1[i] = *(const float4*)&qp1[4 * i];
    q0[i].x *= SCALE; q0[i].y *= SCALE; q0[i].z *= SCALE; q0[i].w *= SCALE;
    q1[i].x *= SCALE; q1[i].y *= SCALE; q1[i].z *= SCALE; q1[i].w *= SCALE;
  }

  // scores: 32 keys per thread (key = kk*8 + qt)
  float sc0[32], sc1[32];
  #pragma unroll
  for (int kk = 0; kk < 32; ++kk) {
    const int row = kk * 8 + qt;
    float a0 = 0.f, a1 = 0.f;
    #pragma unroll
    for (int i = 0; i < 8; ++i) {
      const int ip = i ^ qt;                 // (row&7)==qt
      const float4 kv = *(const float4*)&kls[row][ip << 2];
      a0 = fmaf(q0[i].x, kv.x, a0); a0 = fmaf(q0[i].y, kv.y, a0);
      a0 = fmaf(q0[i].z, kv.z, a0); a0 = fmaf(q0[i].w, kv.w, a0);
      a1 = fmaf(q1[i].x, kv.x, a1); a1 = fmaf(q1[i].y, kv.y, a1);
      a1 = fmaf(q1[i].z, kv.z, a1); a1 = fmaf(q1[i].w, kv.w, a1);
    }
    sc0[kk] = a0; sc1[kk] = a1;
  }

  // softmax (rows split across 8 qt lanes)
  float m0 = sc0[0], m1 = sc1[0];
  #pragma unroll
  for (int kk = 1; kk < 32; ++kk) { m0 = fmaxf(m0, sc0[kk]); m1 = fmaxf(m1, sc1[kk]); }
  m0 = fmaxf(m0, __shfl_xor(m0, 1)); m0 = fmaxf(m0, __shfl_xor(m0, 2)); m0 = fmaxf(m0, __shfl_xor(m0, 4));
  m1 = fmaxf(m1, __shfl_xor(m1, 1)); m1 = fmaxf(m1, __shfl_xor(m1, 2)); m1 = fmaxf(m1, __shfl_xor(m1, 4));
  float l0 = 0.f, l1 = 0.f;
  #pragma unroll
  for (int kk = 0; kk < 32; ++kk) {
    sc0[kk] = __expf(sc0[kk] - m0); l0 += sc0[kk];
    sc1[kk] = __expf(sc1[kk] - m1); l1 += sc1[kk];
  }
  l0 += __shfl_xor(l0, 1); l0 += __shfl_xor(l0, 2); l0 += __shfl_xor(l0, 4);
  l1 += __shfl_xor(l1, 1); l1 += __shfl_xor(l1, 2); l1 += __shfl_xor(l1, 4);

  // PV accumulate (unnormalized)
  float acc0[32], acc1[32];
  #pragma unroll
  for (int i = 0; i < 32; ++i) { acc0[i] = 0.f; acc1[i] = 0.f; }
  #pragma unroll
  for (int kk = 0; kk < 32; ++kk) {
    const int row = kk * 8 + qt;
    const float p0 = sc0[kk], p1 = sc1[kk];
    #pragma unroll
    for (int i = 0; i < 8; ++i) {
      const int ip = i ^ qt;
      const float4 vv = *(const float4*)&vls[row][ip << 2];
      acc0[i*4+0] = fmaf(p0, vv.x, acc0[i*4+0]);
      acc0[i*4+1] = fmaf(p0, vv.y, acc0[i*4+1]);
      acc0[i*4+2] = fmaf(p0, vv.z, acc0[i*4+2]);
      acc0[i*4+3] = fmaf(p0, vv.w, acc0[i*4+3]);
      acc1[i*4+0] = fmaf(p1, vv.x, acc1[i*4+0]);
      acc1[i*4+1] = fmaf(p1, vv.y, acc1[i*4+1]);
      acc1[i*4+2] = fmaf(p1, vv.z, acc1[i*4+2]);
      acc1[i*4+3] = fmaf(p1, vv.w, acc1[i*4+3]);
    }
  }

  // recursive-halving reduction across the 8 qt lanes
  #pragma unroll
  for (int i = 0; i < 16; ++i) {
    float t = (qt & 1) ? acc0[i] : acc0[i + 16];
    float r = __shfl_xor(t, 1);
    float mine = (qt & 1) ? acc0[i + 16] : acc0[i];
    acc0[i] = mine + r;
    float t1_ = (qt & 1) ? acc1[i] : acc1[i + 16];
    float r1_ = __shfl_xor(t1_, 1);
    float mine1 = (qt & 1) ? acc1[i + 16] : acc1[i];
    acc1[i] = mine1 + r1_;
  }
  #pragma unroll
  for (int i = 0; i < 8; ++i) {
    float t = (qt & 2) ? acc0[i] : acc0[i + 8];
    float r = __shfl_xor(t, 2);
    float mine = (qt & 2) ? acc0[i + 8] : acc0[i];
    acc0[i] = mine + r;
    float t1_ = (qt & 2) ? acc1[i] : acc1[i + 8];
    float r1_ = __shfl_xor(t1_, 2);
    float mine1 = (qt & 2) ? acc1[i + 8] : acc1[i];
    acc1[i] = mine1 + r1_;
  }
  #pragma unroll
  for (int i = 0; i < 4; ++i) {
    float t = (qt & 4) ? acc0[i] : acc0[i + 4];
    float r = __shfl_xor(t, 4);
    float mine = (qt & 4) ? acc0[i + 4] : acc0[i];
    acc0[i] = mine + r;
    float t1_ = (qt & 4) ? acc1[i] : acc1[i + 4];
    float r1_ = __shfl_xor(t1_, 4);
    float mine1 = (qt & 4) ? acc1[i + 4] : acc1[i];
    acc1[i] = mine1 + r1_;
  }

  const int cb = ((qt & 1) << 4) | ((qt & 2) << 2) | (qt & 4);
  const float inv0 = 1.f / l0, inv1 = 1.f / l1;
  float4 o0, o1;
  o0.x = acc0[0] * inv0; o0.y = acc0[1] * inv0; o0.z = acc0[2] * inv0; o0.w = acc0[3] * inv0;
  o1.x = acc1[0] * inv1; o1.y = acc1[1] * inv1; o1.z = acc1[2] * inv1; o1.w = acc1[3] * inv1;
  *(float4*)&out_img[((size_t)((n * HWDIM + y0) * HWDIM + x0)) * 256 + head * 32 + cb] = o0;
  *(float4*)&out_img[((size_t)((n * HWDIM + y1) * HWDIM + x1)) * 256 + head * 32 + cb] = o1;
}

// ---------------------------------------------------------------------------
// LEPE: 5x5 depthwise conv over v (image layout), added into attn output.
// grid = N * 7(y-tiles) * 8(channel groups), 256 threads.
// ---------------------------------------------------------------------------
__global__ __launch_bounds__(256) void lepe_add(
    const float* __restrict__ v_img, const float* __restrict__ w,
    const float* __restrict__ bias, float* __restrict__ out_img)
{
  const int blk = blockIdx.x;
  const int n = blk / 56;
  const int rem = blk - n * 56;
  const int yt = rem >> 3;
  const int c8 = rem & 7;
  const int tid = threadIdx.x;
  const int xq = tid >> 5;                // 0..7
  const int c = c8 * 32 + (tid & 31);

  float wk[25];
  #pragma unroll
  for (int i = 0; i < 25; ++i) wk[i] = w[c * 25 + i];
  const float bc = bias[c];

  for (int yy = 0; yy < 8; ++yy) {
    const int y = yt * 8 + yy;
    for (int xx = 0; xx < 7; ++xx) {
      const int x = xq * 7 + xx;
      float acc = bc;
      #pragma unroll
      for (int ky = 0; ky < 5; ++ky) {
        const int sy = y + ky - 2;
        const bool oky = (sy >= 0) && (sy < HWDIM);
        #pragma unroll
        for (int kx = 0; kx < 5; ++kx) {
          const int sx = x + kx - 2;
          float vv = 0.f;
          if (oky && sx >= 0 && sx < HWDIM)
            vv = v_img[((size_t)((n * HWDIM + sy) * HWDIM + sx)) * 256 + c];
          acc = fmaf(wk[ky * 5 + kx], vv, acc);
        }
      }
      out_img[((size_t)((n * HWDIM + y) * HWDIM + x)) * 256 + c] += acc;
    }
  }
}

// ---------------------------------------------------------------------------
extern "C" void kernel_launch(void* const* d_in, const int* in_sizes, int n_in,
                              void* d_out, int out_size, void* d_ws, size_t ws_size,
                              hipStream_t stream)
{
  const float* x      = (const float*)d_in[0];
  const float* W_qkv  = (const float*)d_in[1];
  const float* b_qkv  = (const float*)d_in[2];
  const float* lepe_w = (const float*)d_in[3];
  const float* lepe_b = (const float*)d_in[4];
  const float* W_o    = (const float*)d_in[5];
  const float* b_o    = (const float*)d_in[6];
  float* out = (float*)d_out;

  float* q_img = (float*)d_ws;
  float* k_img = q_img + (size_t)NPIX * 256;
  float* attn  = k_img + (size_t)NPIX * 256;
  float* q_win = attn  + (size_t)NPIX * 256;
  float* k_win = q_win + (size_t)NBATCH * P2 * 256;
  int*   ridx  = (int*)(k_win + (size_t)NBATCH * P2 * 256);
  float* v_img = out;   // reuse output buffer for V (dead before final GEMM writes)

  // 1. QKV projection
  gemm_f32<<<dim3(196, 6), 256, 0, stream>>>(x, W_qkv, b_qkv,
                                             q_img, k_img, v_img, NPIX, 768);
  // 2. window means
  win_means<<<NBATCH * P2, 256, 0, stream>>>(q_img, k_img, q_win, k_win);
  // 3. routing top-k
  routing_topk<<<NBATCH, 256, 0, stream>>>(q_win, k_win, ridx);
  // 4. gathered attention
  attn_kernel<<<NBATCH * P2 * HEADS, 256, 0, stream>>>(q_img, k_img, v_img, ridx, attn);
  // 5. LEPE depthwise conv added into attention output
  lepe_add<<<NBATCH * 7 * 8, 256, 0, stream>>>(v_img, lepe_w, lepe_b, attn);
  // 6. output projection
  gemm_f32<<<dim3(196, 2), 256, 0, stream>>>(attn, W_o, b_o, out, out, out, NPIX, 256);
}